// Round 12
// baseline (180.317 us; speedup 1.0000x reference)
//
#include <hip/hip_runtime.h>
#include <math.h>

#define BB 8
#define NN 1024
#define DD 64
#define EPSF 0.05f
#define MAX_ITER 100
// threshold on SUM of |du| over B*N (reference: mean < 1e-6)
// fixed-point: units of 2^-20; 8.192e-3 * 2^20 = 8589.9 -> 8590
#define ERR_FX_THRESH 8590u
// 1/(eps*ln2) and eps*ln2
#define SCALE_ 28.853900817779268f
#define EPSLN2_ 0.034657359027997264f
#define NBLK 256
#define NPER 32   // blocks per batch barrier

typedef __attribute__((ext_vector_type(8))) short short8;
typedef __attribute__((ext_vector_type(4))) float f32x4;

static __device__ __forceinline__ float fexp2(float x) { return __builtin_amdgcn_exp2f(x); }
static __device__ __forceinline__ float flog2(float x) { return __builtin_amdgcn_logf(x); }
static __device__ __forceinline__ float bflo(unsigned u) { return __uint_as_float(u << 16); }
static __device__ __forceinline__ unsigned short bf16rne(float x) {
    unsigned u = __float_as_uint(x);
    u += 0x7fffu + ((u >> 16) & 1u);
    return (unsigned short)(u >> 16);
}
__device__ __forceinline__ float wave_sum64(float x) {
#pragma unroll
    for (int off = 1; off < 64; off <<= 1) x += __shfl_xor(x, off);
    return x;
}

// ---- metadata: u/v floats (64KB) + cnt64 (12.8KB) = 78,336B past the two 16MB
//      matrices (proven bound). PER-BATCH counter stripes (1600B apart -> distinct
//      XCD-local lines). Protocol law (R2/R3/R6): 32 writers + 32 pollers on ONE
//      line per phase is optimal. Fusion law (R9/R11): in-sink GEMM/W-build tails
//      cost ~+19us (32x redundant W-build + bank conflicts) vs ~13.5us for the
//      separate gemm_final+gap — 3-kernel structure is optimal. ----
// cnt64[b*200+p]: high32 = block-arrival count for phase p of batch b,
//                 low32  = fixed-point err sum (u-phases, 2^-20 units, per-block ceil)
#define CNT64IDX(p, b) ((b) * 200 + (p))

// ---------------- pre-normalize: Qn/Kn = bf16(l2norm(q/k)), ONCE per row (R10-proven) ----------------
__global__ __launch_bounds__(256) void norm_kernel(const float* __restrict__ q,
                                                   const float* __restrict__ k,
                                                   unsigned short* __restrict__ Qn,
                                                   unsigned short* __restrict__ Kn) {
    int tid = threadIdx.x;
    int bi = blockIdx.x;                 // 0..127 -> q rows, 128..255 -> k rows
    const float* src = (bi < 128) ? q : k;
    unsigned short* dst = (bi < 128) ? Qn : Kn;
    int row = (bi & 127) * 64 + (tid >> 2);   // 64 rows per block, 4 threads/row
    int c = tid & 3;                          // 16-float chunk within row
    const float* rp = src + ((size_t)row << 6) + c * 16;
    float4 x0 = ((const float4*)rp)[0];
    float4 x1 = ((const float4*)rp)[1];
    float4 x2 = ((const float4*)rp)[2];
    float4 x3 = ((const float4*)rp)[3];
    float ss = x0.x * x0.x + x0.y * x0.y + x0.z * x0.z + x0.w * x0.w
             + x1.x * x1.x + x1.y * x1.y + x1.z * x1.z + x1.w * x1.w
             + x2.x * x2.x + x2.y * x2.y + x2.z * x2.z + x2.w * x2.w
             + x3.x * x3.x + x3.y * x3.y + x3.z * x3.z + x3.w * x3.w;
    ss += __shfl_xor(ss, 1);
    ss += __shfl_xor(ss, 2);             // 4-lane groups are xor-closed
    float sc = 1.0f / fmaxf(sqrtf(ss), 1e-12f);
    unsigned pk[8];
    pk[0] = (unsigned)bf16rne(x0.x * sc) | ((unsigned)bf16rne(x0.y * sc) << 16);
    pk[1] = (unsigned)bf16rne(x0.z * sc) | ((unsigned)bf16rne(x0.w * sc) << 16);
    pk[2] = (unsigned)bf16rne(x1.x * sc) | ((unsigned)bf16rne(x1.y * sc) << 16);
    pk[3] = (unsigned)bf16rne(x1.z * sc) | ((unsigned)bf16rne(x1.w * sc) << 16);
    pk[4] = (unsigned)bf16rne(x2.x * sc) | ((unsigned)bf16rne(x2.y * sc) << 16);
    pk[5] = (unsigned)bf16rne(x2.z * sc) | ((unsigned)bf16rne(x2.w * sc) << 16);
    pk[6] = (unsigned)bf16rne(x3.x * sc) | ((unsigned)bf16rne(x3.y * sc) << 16);
    pk[7] = (unsigned)bf16rne(x3.z * sc) | ((unsigned)bf16rne(x3.w * sc) << 16);
    unsigned short* op = dst + ((size_t)row << 6) + c * 16;
    ((uint4*)op)[0] = make_uint4(pk[0], pk[1], pk[2], pk[3]);
    ((uint4*)op)[1] = make_uint4(pk[4], pk[5], pk[6], pk[7]);
}

// ---------------- cost + exp via MFMA (R10-proven, verbatim) ----------------
__global__ __launch_bounds__(256) void cost_kernel(const unsigned short* __restrict__ Qn,
                                                   const unsigned short* __restrict__ Kn,
                                                   unsigned short* __restrict__ M,
                                                   unsigned short* __restrict__ MT,
                                                   float* __restrict__ vz) {
    __shared__ __align__(16) unsigned short Qb[64][72];   // pitch 72: 2-way conflict = free
    __shared__ __align__(16) unsigned short Kb[64][72];
    __shared__ __align__(16) unsigned short Ms[64][72];   // M tile staging
    __shared__ __align__(16) unsigned short MsT[64][72];  // MT tile staging
    int b = blockIdx.z;
    int i0 = blockIdx.y * 64, j0 = blockIdx.x * 64;
    int tid = threadIdx.x;
    if (blockIdx.x == 0 && blockIdx.y == 0 && blockIdx.z == 0) {
        // zero v (8192 f) + cnt64 (3200 words) = 11392 words = 2848 float4
        float4 z4 = {0.f, 0.f, 0.f, 0.f};
        for (int i = tid; i < 2848; i += 256) ((float4*)vz)[i] = z4;
    }
    // load 64x64 bf16 tiles of Qn and Kn (8KB each), coalesced uint4
#pragma unroll
    for (int s = 0; s < 2; ++s) {
        int idx = tid + 256 * s;
        int row = idx >> 3, seg = idx & 7;
        *(uint4*)&Qb[row][seg * 8] =
            *(const uint4*)(Qn + (((size_t)b * NN + i0 + row) << 6) + seg * 8);
        *(uint4*)&Kb[row][seg * 8] =
            *(const uint4*)(Kn + (((size_t)b * NN + j0 + row) << 6) + seg * 8);
    }
    __syncthreads();
    int w = tid >> 6, lane = tid & 63;
    int m = lane & 15, qq = lane >> 4;
    int rloc = w * 16;
    short8 a0 = *(const short8*)&Qb[rloc + m][qq * 8];
    short8 a1 = *(const short8*)&Qb[rloc + m][qq * 8 + 32];
    f32x4 acc[4];
#pragma unroll
    for (int nt = 0; nt < 4; ++nt) {
        short8 b0 = *(const short8*)&Kb[nt * 16 + m][qq * 8];
        short8 b1 = *(const short8*)&Kb[nt * 16 + m][qq * 8 + 32];
        f32x4 z = {0.f, 0.f, 0.f, 0.f};
        z = __builtin_amdgcn_mfma_f32_16x16x32_bf16(a0, b0, z, 0, 0, 0);
        acc[nt] = __builtin_amdgcn_mfma_f32_16x16x32_bf16(a1, b1, z, 0, 0, 0);
    }
#pragma unroll
    for (int nt = 0; nt < 4; ++nt) {
        unsigned short us[4];
#pragma unroll
        for (int r = 0; r < 4; ++r)
            us[r] = bf16rne(fexp2((acc[nt][r] - 1.0f) * SCALE_));
#pragma unroll
        for (int r = 0; r < 4; ++r)
            Ms[rloc + qq * 4 + r][nt * 16 + m] = us[r];
        uint2 t;
        t.x = (unsigned)us[0] | ((unsigned)us[1] << 16);
        t.y = (unsigned)us[2] | ((unsigned)us[3] << 16);
        *(uint2*)&MsT[nt * 16 + m][rloc + qq * 4] = t;
    }
    __syncthreads();
    // coalesced stores: 64 rows x 128B each, 8 lanes per row, uint4 x2 per thread
#pragma unroll
    for (int s = 0; s < 2; ++s) {
        int idx = tid + 256 * s;
        int row = idx >> 3, seg = idx & 7;
        *(uint4*)(M + ((size_t)b << 20) + ((size_t)(i0 + row) << 10) + j0 + seg * 8) =
            *(const uint4*)&Ms[row][seg * 8];
        *(uint4*)(MT + ((size_t)b << 20) + ((size_t)(j0 + row) << 10) + i0 + seg * 8) =
            *(const uint4*)&MsT[row][seg * 8];
    }
}

// ---------------- persistent Sinkhorn (R1-proven loop, verbatim) + WT tail (R8-proven) ----------------
#define ACC8(U4, base)                                              \
    s0 = fmaf(bflo(U4.x), wrg[base + 0], s0);                       \
    s1 = fmaf(__uint_as_float(U4.x), wrg[base + 1], s1);            \
    s0 = fmaf(bflo(U4.y), wrg[base + 2], s0);                       \
    s1 = fmaf(__uint_as_float(U4.y), wrg[base + 3], s1);            \
    s0 = fmaf(bflo(U4.z), wrg[base + 4], s0);                       \
    s1 = fmaf(__uint_as_float(U4.z), wrg[base + 5], s1);            \
    s0 = fmaf(bflo(U4.w), wrg[base + 6], s0);                       \
    s1 = fmaf(__uint_as_float(U4.w), wrg[base + 7], s1);

__global__ __launch_bounds__(256, 1) void sink_coop(const unsigned short* __restrict__ M,
                                                    const unsigned short* MT,
                                                    float* __restrict__ u,
                                                    float* __restrict__ v,
                                                    unsigned long long* __restrict__ cnt64,
                                                    const float* __restrict__ V,
                                                    unsigned short* WT,
                                                    float eln) {
    __shared__ __align__(16) float sw[1280];   // pitch-20 padded
    __shared__ float sdel[4];
    __shared__ int sflag;
    int tid = threadIdx.x;
    int w = tid >> 6, lane = tid & 63;
    int b = blockIdx.x & 7;
    int slice = blockIdx.x >> 3;          // 0..31
    int rbase = slice * 32 + w * 8;       // wave's first local row
    const unsigned short* Mb  = M  + ((size_t)b << 20);
    const unsigned short* MTb = MT + ((size_t)b << 20);
    float* ub = u + (b << 10);
    float* vb = v + (b << 10);

    // ---- preload this wave's 8 M-rows + 8 MT-rows into registers (MT dead after) ----
    uint4 mA[8], mB[8], nA[8], nB[8];
#pragma unroll
    for (int r = 0; r < 8; ++r) {
        const uint4* rp = (const uint4*)(Mb + ((size_t)(rbase + r) << 10));
        mA[r] = rp[lane * 2];
        mB[r] = rp[lane * 2 + 1];
        const uint4* tp = (const uint4*)(MTb + ((size_t)(rbase + r) << 10));
        nA[r] = tp[lane * 2];
        nB[r] = tp[lane * 2 + 1];
    }

    float uprev[8], vreg[8];
#pragma unroll
    for (int r = 0; r < 8; ++r) { uprev[r] = 0.f; vreg[r] = 0.f; }

    unsigned myerr = 0xffffffffu;   // tid0: this batch's fixed-point err sum for iter t

    for (int t = 0; t < MAX_ITER; ++t) {
        // ---------- u phase ----------
        {
            float4 ex;
            ex.x = fexp2(__hip_atomic_load(vb + tid * 4 + 0, __ATOMIC_RELAXED, __HIP_MEMORY_SCOPE_AGENT) * SCALE_);
            ex.y = fexp2(__hip_atomic_load(vb + tid * 4 + 1, __ATOMIC_RELAXED, __HIP_MEMORY_SCOPE_AGENT) * SCALE_);
            ex.z = fexp2(__hip_atomic_load(vb + tid * 4 + 2, __ATOMIC_RELAXED, __HIP_MEMORY_SCOPE_AGENT) * SCALE_);
            ex.w = fexp2(__hip_atomic_load(vb + tid * 4 + 3, __ATOMIC_RELAXED, __HIP_MEMORY_SCOPE_AGENT) * SCALE_);
            *(float4*)&sw[tid * 4 + 4 * (tid >> 2)] = ex;
            __syncthreads();
            float wrg[16];
            *(float4*)&wrg[0]  = *(const float4*)&sw[lane * 20 + 0];
            *(float4*)&wrg[4]  = *(const float4*)&sw[lane * 20 + 4];
            *(float4*)&wrg[8]  = *(const float4*)&sw[lane * 20 + 8];
            *(float4*)&wrg[12] = *(const float4*)&sw[lane * 20 + 12];
            float del = 0.f;
#pragma unroll
            for (int rr = 0; rr < 8; ++rr) {
                float s0 = 0.f, s1 = 0.f;
                ACC8(mA[rr], 0)
                ACC8(mB[rr], 8)
                float s = wave_sum64(s0 + s1);
                float un = eln - EPSLN2_ * flog2(s);
                del += fabsf(un - uprev[rr]);
                uprev[rr] = un;
                if (lane == 0)
                    __hip_atomic_store(ub + rbase + rr, un, __ATOMIC_RELAXED, __HIP_MEMORY_SCOPE_AGENT);
            }
            if (lane == 0) sdel[w] = del;
            asm volatile("s_waitcnt vmcnt(0)" ::: "memory");
            __syncthreads();
            if (tid == 0) {
                float dsum = sdel[0] + sdel[1] + sdel[2] + sdel[3];
                unsigned dfx = (unsigned)fminf(dsum * 1048576.0f, 6.0e7f) + 1u;
                unsigned long long* c = cnt64 + CNT64IDX(2 * t, b);
                unsigned long long tot =
                    __hip_atomic_fetch_add(c, (1ULL << 32) | (unsigned long long)dfx,
                                           __ATOMIC_RELAXED, __HIP_MEMORY_SCOPE_AGENT) +
                    ((1ULL << 32) | (unsigned long long)dfx);
                while ((unsigned)(tot >> 32) < NPER) {
                    __builtin_amdgcn_s_sleep(1);
                    tot = __hip_atomic_load(c, __ATOMIC_RELAXED, __HIP_MEMORY_SCOPE_AGENT);
                }
                myerr = (unsigned)tot;   // final once count==NPER; reused in v phase
            }
            __syncthreads();
        }
        // ---------- v phase ----------
        {
            float4 ex;
            ex.x = fexp2(__hip_atomic_load(ub + tid * 4 + 0, __ATOMIC_RELAXED, __HIP_MEMORY_SCOPE_AGENT) * SCALE_);
            ex.y = fexp2(__hip_atomic_load(ub + tid * 4 + 1, __ATOMIC_RELAXED, __HIP_MEMORY_SCOPE_AGENT) * SCALE_);
            ex.z = fexp2(__hip_atomic_load(ub + tid * 4 + 2, __ATOMIC_RELAXED, __HIP_MEMORY_SCOPE_AGENT) * SCALE_);
            ex.w = fexp2(__hip_atomic_load(ub + tid * 4 + 3, __ATOMIC_RELAXED, __HIP_MEMORY_SCOPE_AGENT) * SCALE_);
            *(float4*)&sw[tid * 4 + 4 * (tid >> 2)] = ex;
            __syncthreads();
            float wrg[16];
            *(float4*)&wrg[0]  = *(const float4*)&sw[lane * 20 + 0];
            *(float4*)&wrg[4]  = *(const float4*)&sw[lane * 20 + 4];
            *(float4*)&wrg[8]  = *(const float4*)&sw[lane * 20 + 8];
            *(float4*)&wrg[12] = *(const float4*)&sw[lane * 20 + 12];
#pragma unroll
            for (int rr = 0; rr < 8; ++rr) {
                float s0 = 0.f, s1 = 0.f;
                ACC8(nA[rr], 0)
                ACC8(nB[rr], 8)
                float s = wave_sum64(s0 + s1);
                float vn = eln - EPSLN2_ * flog2(s);
                vreg[rr] = vn;   // keep final v in registers for the WT tail
                if (lane == 0)
                    __hip_atomic_store(vb + rbase + rr, vn, __ATOMIC_RELAXED, __HIP_MEMORY_SCOPE_AGENT);
            }
            asm volatile("s_waitcnt vmcnt(0)" ::: "memory");
            __syncthreads();
            if (tid == 0) {
                unsigned long long* c = cnt64 + CNT64IDX(2 * t + 1, b);
                unsigned long long tot =
                    __hip_atomic_fetch_add(c, 1ULL << 32, __ATOMIC_RELAXED, __HIP_MEMORY_SCOPE_AGENT) +
                    (1ULL << 32);
                while ((unsigned)(tot >> 32) < NPER) {
                    __builtin_amdgcn_s_sleep(1);
                    tot = __hip_atomic_load(c, __ATOMIC_RELAXED, __HIP_MEMORY_SCOPE_AGENT);
                }
                int brk = 0;
                if (myerr < ERR_FX_THRESH) {
                    // rare path: no batch can break before the global sum crosses the
                    // threshold, so every batch's u-counter for t reaches NPER.
                    unsigned long long s = 0;
                    for (int bb = 0; bb < 8; ++bb) {
                        unsigned long long tv = __hip_atomic_load(cnt64 + CNT64IDX(2 * t, bb),
                                                                  __ATOMIC_RELAXED, __HIP_MEMORY_SCOPE_AGENT);
                        while ((unsigned)(tv >> 32) < NPER) {
                            __builtin_amdgcn_s_sleep(1);
                            tv = __hip_atomic_load(cnt64 + CNT64IDX(2 * t, bb),
                                                   __ATOMIC_RELAXED, __HIP_MEMORY_SCOPE_AGENT);
                        }
                        s += (unsigned long long)(unsigned)tv;
                    }
                    brk = (s < (unsigned long long)ERR_FX_THRESH);
                }
                sflag = brk;
            }
            __syncthreads();
            if (sflag) break;
        }
    }

    // ---------------- WT tail (R8-proven): WT[b][d][j] = bf16(exp2(v_j*S)*V[b][j][d]) ----------------
    {
        __syncthreads();   // sw exchange reads complete before reuse
        float* swj = &sw[1152];                       // 32 floats (tile uses floats 0..1151)
        unsigned short* T = (unsigned short*)sw;      // [64 d][36] bf16 tile (4608B)
#pragma unroll
        for (int r = 0; r < 8; ++r)
            if (lane == r) swj[w * 8 + r] = fexp2(vreg[r] * SCALE_);
        __syncthreads();
        int jr = lane >> 3;          // 0..7: row within wave
        int seg = lane & 7;          // 0..7: d-segment (8 d's)
        int j = rbase + jr;          // global j
        float wj = swj[w * 8 + jr];
        const float* Vp = V + ((((size_t)(b << 10)) + j) << 6) + seg * 8;
        float4 x0 = *(const float4*)(Vp);
        float4 x1 = *(const float4*)(Vp + 4);
        int jloc = w * 8 + jr;
        int d0 = seg * 8;
        T[(d0 + 0) * 36 + jloc] = bf16rne(x0.x * wj);
        T[(d0 + 1) * 36 + jloc] = bf16rne(x0.y * wj);
        T[(d0 + 2) * 36 + jloc] = bf16rne(x0.z * wj);
        T[(d0 + 3) * 36 + jloc] = bf16rne(x0.w * wj);
        T[(d0 + 4) * 36 + jloc] = bf16rne(x1.x * wj);
        T[(d0 + 5) * 36 + jloc] = bf16rne(x1.y * wj);
        T[(d0 + 6) * 36 + jloc] = bf16rne(x1.z * wj);
        T[(d0 + 7) * 36 + jloc] = bf16rne(x1.w * wj);
        __syncthreads();
        int d = tid >> 2, q4 = tid & 3;
        const unsigned short* tr = &T[d * 36 + q4 * 8];
        uint4 o;
        o.x = (unsigned)tr[0] | ((unsigned)tr[1] << 16);
        o.y = (unsigned)tr[2] | ((unsigned)tr[3] << 16);
        o.z = (unsigned)tr[4] | ((unsigned)tr[5] << 16);
        o.w = (unsigned)tr[6] | ((unsigned)tr[7] << 16);
        *(uint4*)(WT + ((size_t)b << 16) + ((size_t)d << 10) + slice * 32 + q4 * 8) = o;
    }
}

// ---------------- MFMA epilogue: out = diag(a) * (M @ W) + V ----------------
// 512 blocks (16-row tiles): 2 blocks/CU -> 2 waves/SIMD, double the latency
// hiding of the old 256-block config (1 wave/SIMD) for this load-latency-bound
// kernel. Per-output-element accumulation order unchanged -> bit-identical.
__global__ __launch_bounds__(256) void gemm_final(const unsigned short* __restrict__ M,
                                                  const unsigned short* __restrict__ WT,
                                                  const float* __restrict__ u,
                                                  const float* __restrict__ V,
                                                  float* __restrict__ out) {
    __shared__ float sa[16];
    int tid = threadIdx.x;
    int w = tid >> 6, lane = tid & 63;
    int b = blockIdx.x & 7, mt = blockIdx.x >> 3;   // mt: 0..63, 16-row tiles
    if (tid < 16) sa[tid] = fexp2(u[(b << 10) + mt * 16 + tid] * SCALE_);
    __syncthreads();
    int m = lane & 15, q = lane >> 4;
    int nbase = w * 16;                              // wave's 16-col strip
    const unsigned short* Ma = M + ((size_t)b << 20) + ((size_t)(mt * 16 + m) << 10) + q * 8;
    const unsigned short* W0 = WT + ((size_t)b << 16) + ((size_t)(nbase + m) << 10) + q * 8;
    f32x4 acc0 = {0.f, 0.f, 0.f, 0.f};
#pragma unroll 8
    for (int k0 = 0; k0 < NN; k0 += 32) {
        short8 af = *(const short8*)(Ma + k0);
        short8 b0 = *(const short8*)(W0 + k0);
        acc0 = __builtin_amdgcn_mfma_f32_16x16x32_bf16(af, b0, acc0, 0, 0, 0);
    }
#pragma unroll
    for (int r = 0; r < 4; ++r) {
        int lrow = q * 4 + r;
        int gm = mt * 16 + lrow;
        float a = sa[lrow];
        size_t base = (((size_t)b << 10) + gm) * DD;
        int n0 = nbase + m;
        out[base + n0] = fmaf(a, acc0[r], V[base + n0]);
    }
}

extern "C" void kernel_launch(void* const* d_in, const int* in_sizes, int n_in,
                              void* d_out, int out_size, void* d_ws, size_t ws_size,
                              hipStream_t stream) {
    const float* q = (const float*)d_in[0];
    const float* k = (const float*)d_in[1];
    const float* V = (const float*)d_in[2];
    float* out = (float*)d_out;

    char* ws = (char*)d_ws;
    const size_t MB16 = (size_t)BB * NN * NN * sizeof(unsigned short);   // 16 MB
    unsigned short* M  = (unsigned short*)ws;
    unsigned short* MT = (unsigned short*)(ws + MB16);
    unsigned short* WT = MT;                  // MT dead after sink preload; WT overwrites it
    float* u   = (float*)(ws + 2 * MB16);
    float* v   = u + BB * NN;                               // u+v = 64 KiB
    unsigned long long* cnt64 = (unsigned long long*)(v + BB * NN);   // 1600 u64 = 12,800 B
    // u, v, cnt64 contiguous: 65,536 + 12,800 = 78,336 B (proven bound)

    // out-as-scratch: Qn (1MB) || Kn (1MB) = exactly out's 2MB; out is only
    // written by gemm_final, after the last Qn/Kn read (stream-ordered).
    unsigned short* Qn = (unsigned short*)out;
    unsigned short* Kn = Qn + (size_t)BB * NN * DD;

    norm_kernel<<<256, 256, 0, stream>>>(q, k, Qn, Kn);

    // metadata zeroing folded into cost_kernel block (0,0,0): v + cnt64 only
    cost_kernel<<<dim3(16, 16, 8), 256, 0, stream>>>(Qn, Kn, M, MT, v);

    float eln = EPSF * logf(1.0f / NN + 1e-8f);
    // REGULAR launch: barrier is hand-rolled, co-residency is de-facto guaranteed at
    // 256 blocks / 256 CUs (~132 VGPR, 5.6KB LDS). Failure mode if placement ever
    // splits: visible hang, not silent corruption.
    sink_coop<<<dim3(NBLK), dim3(256), 0, stream>>>(M, MT, u, v, cnt64, V, WT, eln);

    gemm_final<<<512, 256, 0, stream>>>(M, WT, u, V, out);
}

// Round 13
// 175.628 us; speedup vs baseline: 1.0267x; 1.0267x over previous
//
#include <hip/hip_runtime.h>
#include <math.h>

#define BB 8
#define NN 1024
#define DD 64
#define EPSF 0.05f
#define MAX_ITER 100
// threshold on SUM of |du| over B*N (reference: mean < 1e-6)
// fixed-point: units of 2^-20; 8.192e-3 * 2^20 = 8589.9 -> 8590
#define ERR_FX_THRESH 8590u
// 1/(eps*ln2) and eps*ln2
#define SCALE_ 28.853900817779268f
#define EPSLN2_ 0.034657359027997264f
#define NBLK 256
#define NPER 32   // blocks per batch barrier

typedef __attribute__((ext_vector_type(8))) short short8;
typedef __attribute__((ext_vector_type(4))) float f32x4;

static __device__ __forceinline__ float fexp2(float x) { return __builtin_amdgcn_exp2f(x); }
static __device__ __forceinline__ float flog2(float x) { return __builtin_amdgcn_logf(x); }
static __device__ __forceinline__ float bflo(unsigned u) { return __uint_as_float(u << 16); }
static __device__ __forceinline__ unsigned short bf16rne(float x) {
    unsigned u = __float_as_uint(x);
    u += 0x7fffu + ((u >> 16) & 1u);
    return (unsigned short)(u >> 16);
}
__device__ __forceinline__ float wave_sum64(float x) {
#pragma unroll
    for (int off = 1; off < 64; off <<= 1) x += __shfl_xor(x, off);
    return x;
}

// ---- metadata: u/v floats (64KB) + cnt64 (12.8KB) = 78,336B past the two 16MB
//      matrices (proven bound). PER-BATCH counter stripes (1600B apart -> distinct
//      XCD-local lines). Protocol law (R2/R3/R6): 32 writers + 32 pollers on ONE
//      line per phase is optimal. Fusion law (R9/R11): in-sink GEMM/W-build tails
//      cost ~+19us vs ~13.5us for the separate gemm_final+gap. Occupancy law (R12):
//      gemm_final at 256 blocks is already latency-optimal. ----
// cnt64[b*200+p]: high32 = block-arrival count for phase p of batch b,
//                 low32  = fixed-point err sum (u-phases, 2^-20 units, per-block ceil)
#define CNT64IDX(p, b) ((b) * 200 + (p))

// ---------------- pre-normalize: Qn/Kn = bf16(l2norm(q/k)), ONCE per row (R10-proven) ----------------
__global__ __launch_bounds__(256) void norm_kernel(const float* __restrict__ q,
                                                   const float* __restrict__ k,
                                                   unsigned short* __restrict__ Qn,
                                                   unsigned short* __restrict__ Kn) {
    int tid = threadIdx.x;
    int bi = blockIdx.x;                 // 0..127 -> q rows, 128..255 -> k rows
    const float* src = (bi < 128) ? q : k;
    unsigned short* dst = (bi < 128) ? Qn : Kn;
    int row = (bi & 127) * 64 + (tid >> 2);   // 64 rows per block, 4 threads/row
    int c = tid & 3;                          // 16-float chunk within row
    const float* rp = src + ((size_t)row << 6) + c * 16;
    float4 x0 = ((const float4*)rp)[0];
    float4 x1 = ((const float4*)rp)[1];
    float4 x2 = ((const float4*)rp)[2];
    float4 x3 = ((const float4*)rp)[3];
    float ss = x0.x * x0.x + x0.y * x0.y + x0.z * x0.z + x0.w * x0.w
             + x1.x * x1.x + x1.y * x1.y + x1.z * x1.z + x1.w * x1.w
             + x2.x * x2.x + x2.y * x2.y + x2.z * x2.z + x2.w * x2.w
             + x3.x * x3.x + x3.y * x3.y + x3.z * x3.z + x3.w * x3.w;
    ss += __shfl_xor(ss, 1);
    ss += __shfl_xor(ss, 2);             // 4-lane groups are xor-closed
    float sc = 1.0f / fmaxf(sqrtf(ss), 1e-12f);
    unsigned pk[8];
    pk[0] = (unsigned)bf16rne(x0.x * sc) | ((unsigned)bf16rne(x0.y * sc) << 16);
    pk[1] = (unsigned)bf16rne(x0.z * sc) | ((unsigned)bf16rne(x0.w * sc) << 16);
    pk[2] = (unsigned)bf16rne(x1.x * sc) | ((unsigned)bf16rne(x1.y * sc) << 16);
    pk[3] = (unsigned)bf16rne(x1.z * sc) | ((unsigned)bf16rne(x1.w * sc) << 16);
    pk[4] = (unsigned)bf16rne(x2.x * sc) | ((unsigned)bf16rne(x2.y * sc) << 16);
    pk[5] = (unsigned)bf16rne(x2.z * sc) | ((unsigned)bf16rne(x2.w * sc) << 16);
    pk[6] = (unsigned)bf16rne(x3.x * sc) | ((unsigned)bf16rne(x3.y * sc) << 16);
    pk[7] = (unsigned)bf16rne(x3.z * sc) | ((unsigned)bf16rne(x3.w * sc) << 16);
    unsigned short* op = dst + ((size_t)row << 6) + c * 16;
    ((uint4*)op)[0] = make_uint4(pk[0], pk[1], pk[2], pk[3]);
    ((uint4*)op)[1] = make_uint4(pk[4], pk[5], pk[6], pk[7]);
}

// ---------------- cost + exp via MFMA (R10-proven, verbatim) ----------------
__global__ __launch_bounds__(256) void cost_kernel(const unsigned short* __restrict__ Qn,
                                                   const unsigned short* __restrict__ Kn,
                                                   unsigned short* __restrict__ M,
                                                   unsigned short* __restrict__ MT,
                                                   float* __restrict__ vz) {
    __shared__ __align__(16) unsigned short Qb[64][72];   // pitch 72: 2-way conflict = free
    __shared__ __align__(16) unsigned short Kb[64][72];
    __shared__ __align__(16) unsigned short Ms[64][72];   // M tile staging
    __shared__ __align__(16) unsigned short MsT[64][72];  // MT tile staging
    int b = blockIdx.z;
    int i0 = blockIdx.y * 64, j0 = blockIdx.x * 64;
    int tid = threadIdx.x;
    if (blockIdx.x == 0 && blockIdx.y == 0 && blockIdx.z == 0) {
        // zero v (8192 f) + cnt64 (3200 words) = 11392 words = 2848 float4
        float4 z4 = {0.f, 0.f, 0.f, 0.f};
        for (int i = tid; i < 2848; i += 256) ((float4*)vz)[i] = z4;
    }
    // load 64x64 bf16 tiles of Qn and Kn (8KB each), coalesced uint4
#pragma unroll
    for (int s = 0; s < 2; ++s) {
        int idx = tid + 256 * s;
        int row = idx >> 3, seg = idx & 7;
        *(uint4*)&Qb[row][seg * 8] =
            *(const uint4*)(Qn + (((size_t)b * NN + i0 + row) << 6) + seg * 8);
        *(uint4*)&Kb[row][seg * 8] =
            *(const uint4*)(Kn + (((size_t)b * NN + j0 + row) << 6) + seg * 8);
    }
    __syncthreads();
    int w = tid >> 6, lane = tid & 63;
    int m = lane & 15, qq = lane >> 4;
    int rloc = w * 16;
    short8 a0 = *(const short8*)&Qb[rloc + m][qq * 8];
    short8 a1 = *(const short8*)&Qb[rloc + m][qq * 8 + 32];
    f32x4 acc[4];
#pragma unroll
    for (int nt = 0; nt < 4; ++nt) {
        short8 b0 = *(const short8*)&Kb[nt * 16 + m][qq * 8];
        short8 b1 = *(const short8*)&Kb[nt * 16 + m][qq * 8 + 32];
        f32x4 z = {0.f, 0.f, 0.f, 0.f};
        z = __builtin_amdgcn_mfma_f32_16x16x32_bf16(a0, b0, z, 0, 0, 0);
        acc[nt] = __builtin_amdgcn_mfma_f32_16x16x32_bf16(a1, b1, z, 0, 0, 0);
    }
#pragma unroll
    for (int nt = 0; nt < 4; ++nt) {
        unsigned short us[4];
#pragma unroll
        for (int r = 0; r < 4; ++r)
            us[r] = bf16rne(fexp2((acc[nt][r] - 1.0f) * SCALE_));
#pragma unroll
        for (int r = 0; r < 4; ++r)
            Ms[rloc + qq * 4 + r][nt * 16 + m] = us[r];
        uint2 t;
        t.x = (unsigned)us[0] | ((unsigned)us[1] << 16);
        t.y = (unsigned)us[2] | ((unsigned)us[3] << 16);
        *(uint2*)&MsT[nt * 16 + m][rloc + qq * 4] = t;
    }
    __syncthreads();
    // coalesced stores: 64 rows x 128B each, 8 lanes per row, uint4 x2 per thread
#pragma unroll
    for (int s = 0; s < 2; ++s) {
        int idx = tid + 256 * s;
        int row = idx >> 3, seg = idx & 7;
        *(uint4*)(M + ((size_t)b << 20) + ((size_t)(i0 + row) << 10) + j0 + seg * 8) =
            *(const uint4*)&Ms[row][seg * 8];
        *(uint4*)(MT + ((size_t)b << 20) + ((size_t)(j0 + row) << 10) + i0 + seg * 8) =
            *(const uint4*)&MsT[row][seg * 8];
    }
}

// ---------------- persistent Sinkhorn (R1-proven loop, verbatim) + WT tail (R8-proven) ----------------
#define ACC8(U4, base)                                              \
    s0 = fmaf(bflo(U4.x), wrg[base + 0], s0);                       \
    s1 = fmaf(__uint_as_float(U4.x), wrg[base + 1], s1);            \
    s0 = fmaf(bflo(U4.y), wrg[base + 2], s0);                       \
    s1 = fmaf(__uint_as_float(U4.y), wrg[base + 3], s1);            \
    s0 = fmaf(bflo(U4.z), wrg[base + 4], s0);                       \
    s1 = fmaf(__uint_as_float(U4.z), wrg[base + 5], s1);            \
    s0 = fmaf(bflo(U4.w), wrg[base + 6], s0);                       \
    s1 = fmaf(__uint_as_float(U4.w), wrg[base + 7], s1);

__global__ __launch_bounds__(256, 1) void sink_coop(const unsigned short* __restrict__ M,
                                                    const unsigned short* MT,
                                                    float* __restrict__ u,
                                                    float* __restrict__ v,
                                                    unsigned long long* __restrict__ cnt64,
                                                    const float* __restrict__ V,
                                                    unsigned short* WT,
                                                    float eln) {
    __shared__ __align__(16) float sw[1280];   // pitch-20 padded
    __shared__ float sdel[4];
    __shared__ int sflag;
    int tid = threadIdx.x;
    int w = tid >> 6, lane = tid & 63;
    int b = blockIdx.x & 7;
    int slice = blockIdx.x >> 3;          // 0..31
    int rbase = slice * 32 + w * 8;       // wave's first local row
    const unsigned short* Mb  = M  + ((size_t)b << 20);
    const unsigned short* MTb = MT + ((size_t)b << 20);
    float* ub = u + (b << 10);
    float* vb = v + (b << 10);

    // ---- preload this wave's 8 M-rows + 8 MT-rows into registers (MT dead after) ----
    uint4 mA[8], mB[8], nA[8], nB[8];
#pragma unroll
    for (int r = 0; r < 8; ++r) {
        const uint4* rp = (const uint4*)(Mb + ((size_t)(rbase + r) << 10));
        mA[r] = rp[lane * 2];
        mB[r] = rp[lane * 2 + 1];
        const uint4* tp = (const uint4*)(MTb + ((size_t)(rbase + r) << 10));
        nA[r] = tp[lane * 2];
        nB[r] = tp[lane * 2 + 1];
    }

    float uprev[8], vreg[8];
#pragma unroll
    for (int r = 0; r < 8; ++r) { uprev[r] = 0.f; vreg[r] = 0.f; }

    unsigned myerr = 0xffffffffu;   // tid0: this batch's fixed-point err sum for iter t

    for (int t = 0; t < MAX_ITER; ++t) {
        // ---------- u phase ----------
        {
            float4 ex;
            ex.x = fexp2(__hip_atomic_load(vb + tid * 4 + 0, __ATOMIC_RELAXED, __HIP_MEMORY_SCOPE_AGENT) * SCALE_);
            ex.y = fexp2(__hip_atomic_load(vb + tid * 4 + 1, __ATOMIC_RELAXED, __HIP_MEMORY_SCOPE_AGENT) * SCALE_);
            ex.z = fexp2(__hip_atomic_load(vb + tid * 4 + 2, __ATOMIC_RELAXED, __HIP_MEMORY_SCOPE_AGENT) * SCALE_);
            ex.w = fexp2(__hip_atomic_load(vb + tid * 4 + 3, __ATOMIC_RELAXED, __HIP_MEMORY_SCOPE_AGENT) * SCALE_);
            *(float4*)&sw[tid * 4 + 4 * (tid >> 2)] = ex;
            __syncthreads();
            float wrg[16];
            *(float4*)&wrg[0]  = *(const float4*)&sw[lane * 20 + 0];
            *(float4*)&wrg[4]  = *(const float4*)&sw[lane * 20 + 4];
            *(float4*)&wrg[8]  = *(const float4*)&sw[lane * 20 + 8];
            *(float4*)&wrg[12] = *(const float4*)&sw[lane * 20 + 12];
            float del = 0.f;
#pragma unroll
            for (int rr = 0; rr < 8; ++rr) {
                float s0 = 0.f, s1 = 0.f;
                ACC8(mA[rr], 0)
                ACC8(mB[rr], 8)
                float s = wave_sum64(s0 + s1);
                float un = eln - EPSLN2_ * flog2(s);
                del += fabsf(un - uprev[rr]);
                uprev[rr] = un;
                if (lane == 0)
                    __hip_atomic_store(ub + rbase + rr, un, __ATOMIC_RELAXED, __HIP_MEMORY_SCOPE_AGENT);
            }
            if (lane == 0) sdel[w] = del;
            asm volatile("s_waitcnt vmcnt(0)" ::: "memory");
            __syncthreads();
            if (tid == 0) {
                float dsum = sdel[0] + sdel[1] + sdel[2] + sdel[3];
                unsigned dfx = (unsigned)fminf(dsum * 1048576.0f, 6.0e7f) + 1u;
                unsigned long long* c = cnt64 + CNT64IDX(2 * t, b);
                unsigned long long tot =
                    __hip_atomic_fetch_add(c, (1ULL << 32) | (unsigned long long)dfx,
                                           __ATOMIC_RELAXED, __HIP_MEMORY_SCOPE_AGENT) +
                    ((1ULL << 32) | (unsigned long long)dfx);
                while ((unsigned)(tot >> 32) < NPER) {
                    __builtin_amdgcn_s_sleep(1);
                    tot = __hip_atomic_load(c, __ATOMIC_RELAXED, __HIP_MEMORY_SCOPE_AGENT);
                }
                myerr = (unsigned)tot;   // final once count==NPER; reused in v phase
            }
            __syncthreads();
        }
        // ---------- v phase ----------
        {
            float4 ex;
            ex.x = fexp2(__hip_atomic_load(ub + tid * 4 + 0, __ATOMIC_RELAXED, __HIP_MEMORY_SCOPE_AGENT) * SCALE_);
            ex.y = fexp2(__hip_atomic_load(ub + tid * 4 + 1, __ATOMIC_RELAXED, __HIP_MEMORY_SCOPE_AGENT) * SCALE_);
            ex.z = fexp2(__hip_atomic_load(ub + tid * 4 + 2, __ATOMIC_RELAXED, __HIP_MEMORY_SCOPE_AGENT) * SCALE_);
            ex.w = fexp2(__hip_atomic_load(ub + tid * 4 + 3, __ATOMIC_RELAXED, __HIP_MEMORY_SCOPE_AGENT) * SCALE_);
            *(float4*)&sw[tid * 4 + 4 * (tid >> 2)] = ex;
            __syncthreads();
            float wrg[16];
            *(float4*)&wrg[0]  = *(const float4*)&sw[lane * 20 + 0];
            *(float4*)&wrg[4]  = *(const float4*)&sw[lane * 20 + 4];
            *(float4*)&wrg[8]  = *(const float4*)&sw[lane * 20 + 8];
            *(float4*)&wrg[12] = *(const float4*)&sw[lane * 20 + 12];
#pragma unroll
            for (int rr = 0; rr < 8; ++rr) {
                float s0 = 0.f, s1 = 0.f;
                ACC8(nA[rr], 0)
                ACC8(nB[rr], 8)
                float s = wave_sum64(s0 + s1);
                float vn = eln - EPSLN2_ * flog2(s);
                vreg[rr] = vn;   // keep final v in registers for the WT tail
                if (lane == 0)
                    __hip_atomic_store(vb + rbase + rr, vn, __ATOMIC_RELAXED, __HIP_MEMORY_SCOPE_AGENT);
            }
            asm volatile("s_waitcnt vmcnt(0)" ::: "memory");
            __syncthreads();
            if (tid == 0) {
                unsigned long long* c = cnt64 + CNT64IDX(2 * t + 1, b);
                unsigned long long tot =
                    __hip_atomic_fetch_add(c, 1ULL << 32, __ATOMIC_RELAXED, __HIP_MEMORY_SCOPE_AGENT) +
                    (1ULL << 32);
                while ((unsigned)(tot >> 32) < NPER) {
                    __builtin_amdgcn_s_sleep(1);
                    tot = __hip_atomic_load(c, __ATOMIC_RELAXED, __HIP_MEMORY_SCOPE_AGENT);
                }
                int brk = 0;
                if (myerr < ERR_FX_THRESH) {
                    // rare path: no batch can break before the global sum crosses the
                    // threshold, so every batch's u-counter for t reaches NPER.
                    unsigned long long s = 0;
                    for (int bb = 0; bb < 8; ++bb) {
                        unsigned long long tv = __hip_atomic_load(cnt64 + CNT64IDX(2 * t, bb),
                                                                  __ATOMIC_RELAXED, __HIP_MEMORY_SCOPE_AGENT);
                        while ((unsigned)(tv >> 32) < NPER) {
                            __builtin_amdgcn_s_sleep(1);
                            tv = __hip_atomic_load(cnt64 + CNT64IDX(2 * t, bb),
                                                   __ATOMIC_RELAXED, __HIP_MEMORY_SCOPE_AGENT);
                        }
                        s += (unsigned long long)(unsigned)tv;
                    }
                    brk = (s < (unsigned long long)ERR_FX_THRESH);
                }
                sflag = brk;
            }
            __syncthreads();
            if (sflag) break;
        }
    }

    // ---------------- WT tail (R8-proven): WT[b][d][j] = bf16(exp2(v_j*S)*V[b][j][d]) ----------------
    {
        __syncthreads();   // sw exchange reads complete before reuse
        float* swj = &sw[1152];                       // 32 floats (tile uses floats 0..1151)
        unsigned short* T = (unsigned short*)sw;      // [64 d][36] bf16 tile (4608B)
#pragma unroll
        for (int r = 0; r < 8; ++r)
            if (lane == r) swj[w * 8 + r] = fexp2(vreg[r] * SCALE_);
        __syncthreads();
        int jr = lane >> 3;          // 0..7: row within wave
        int seg = lane & 7;          // 0..7: d-segment (8 d's)
        int j = rbase + jr;          // global j
        float wj = swj[w * 8 + jr];
        const float* Vp = V + ((((size_t)(b << 10)) + j) << 6) + seg * 8;
        float4 x0 = *(const float4*)(Vp);
        float4 x1 = *(const float4*)(Vp + 4);
        int jloc = w * 8 + jr;
        int d0 = seg * 8;
        T[(d0 + 0) * 36 + jloc] = bf16rne(x0.x * wj);
        T[(d0 + 1) * 36 + jloc] = bf16rne(x0.y * wj);
        T[(d0 + 2) * 36 + jloc] = bf16rne(x0.z * wj);
        T[(d0 + 3) * 36 + jloc] = bf16rne(x0.w * wj);
        T[(d0 + 4) * 36 + jloc] = bf16rne(x1.x * wj);
        T[(d0 + 5) * 36 + jloc] = bf16rne(x1.y * wj);
        T[(d0 + 6) * 36 + jloc] = bf16rne(x1.z * wj);
        T[(d0 + 7) * 36 + jloc] = bf16rne(x1.w * wj);
        __syncthreads();
        int d = tid >> 2, q4 = tid & 3;
        const unsigned short* tr = &T[d * 36 + q4 * 8];
        uint4 o;
        o.x = (unsigned)tr[0] | ((unsigned)tr[1] << 16);
        o.y = (unsigned)tr[2] | ((unsigned)tr[3] << 16);
        o.z = (unsigned)tr[4] | ((unsigned)tr[5] << 16);
        o.w = (unsigned)tr[6] | ((unsigned)tr[7] << 16);
        *(uint4*)(WT + ((size_t)b << 16) + ((size_t)d << 10) + slice * 32 + q4 * 8) = o;
    }
}

// ---------------- MFMA epilogue: out = diag(a) * (M @ W) + V (R10-proven, verbatim) ----------------
__global__ __launch_bounds__(256) void gemm_final(const unsigned short* __restrict__ M,
                                                  const unsigned short* __restrict__ WT,
                                                  const float* __restrict__ u,
                                                  const float* __restrict__ V,
                                                  float* __restrict__ out) {
    __shared__ float sa[32];
    int tid = threadIdx.x;
    int w = tid >> 6, lane = tid & 63;
    int b = blockIdx.x & 7, mt = blockIdx.x >> 3;
    if (tid < 32) sa[tid] = fexp2(u[(b << 10) + mt * 32 + tid] * SCALE_);
    __syncthreads();
    int m = lane & 15, q = lane >> 4;
    int rloc = (w & 1) * 16;
    int nbase = (w >> 1) * 32;
    const unsigned short* Ma = M + ((size_t)b << 20) + ((size_t)(mt * 32 + rloc + m) << 10) + q * 8;
    const unsigned short* W0 = WT + ((size_t)b << 16) + ((size_t)(nbase + m) << 10) + q * 8;
    const unsigned short* W1 = W0 + (16 << 10);
    f32x4 acc0 = {0.f, 0.f, 0.f, 0.f}, acc1 = {0.f, 0.f, 0.f, 0.f};
#pragma unroll 4
    for (int k0 = 0; k0 < NN; k0 += 32) {
        short8 af = *(const short8*)(Ma + k0);
        short8 b0 = *(const short8*)(W0 + k0);
        short8 b1 = *(const short8*)(W1 + k0);
        acc0 = __builtin_amdgcn_mfma_f32_16x16x32_bf16(af, b0, acc0, 0, 0, 0);
        acc1 = __builtin_amdgcn_mfma_f32_16x16x32_bf16(af, b1, acc1, 0, 0, 0);
    }
#pragma unroll
    for (int r = 0; r < 4; ++r) {
        int lrow = rloc + q * 4 + r;
        int gm = mt * 32 + lrow;
        float a = sa[lrow];
        size_t base = (((size_t)b << 10) + gm) * DD;
        int n0 = nbase + m;
        out[base + n0]      = fmaf(a, acc0[r], V[base + n0]);
        out[base + n0 + 16] = fmaf(a, acc1[r], V[base + n0 + 16]);
    }
}

extern "C" void kernel_launch(void* const* d_in, const int* in_sizes, int n_in,
                              void* d_out, int out_size, void* d_ws, size_t ws_size,
                              hipStream_t stream) {
    const float* q = (const float*)d_in[0];
    const float* k = (const float*)d_in[1];
    const float* V = (const float*)d_in[2];
    float* out = (float*)d_out;

    char* ws = (char*)d_ws;
    const size_t MB16 = (size_t)BB * NN * NN * sizeof(unsigned short);   // 16 MB
    unsigned short* M  = (unsigned short*)ws;
    unsigned short* MT = (unsigned short*)(ws + MB16);
    unsigned short* WT = MT;                  // MT dead after sink preload; WT overwrites it
    float* u   = (float*)(ws + 2 * MB16);
    float* v   = u + BB * NN;                               // u+v = 64 KiB
    unsigned long long* cnt64 = (unsigned long long*)(v + BB * NN);   // 1600 u64 = 12,800 B
    // u, v, cnt64 contiguous: 65,536 + 12,800 = 78,336 B (proven bound)

    // out-as-scratch: Qn (1MB) || Kn (1MB) = exactly out's 2MB; out is only
    // written by gemm_final, after the last Qn/Kn read (stream-ordered).
    unsigned short* Qn = (unsigned short*)out;
    unsigned short* Kn = Qn + (size_t)BB * NN * DD;

    norm_kernel<<<256, 256, 0, stream>>>(q, k, Qn, Kn);

    // metadata zeroing folded into cost_kernel block (0,0,0): v + cnt64 only
    cost_kernel<<<dim3(16, 16, 8), 256, 0, stream>>>(Qn, Kn, M, MT, v);

    float eln = EPSF * logf(1.0f / NN + 1e-8f);
    // REGULAR launch: barrier is hand-rolled, co-residency is de-facto guaranteed at
    // 256 blocks / 256 CUs (~132 VGPR, 5.6KB LDS). Failure mode if placement ever
    // splits: visible hang, not silent corruption.
    sink_coop<<<dim3(NBLK), dim3(256), 0, stream>>>(M, MT, u, v, cnt64, V, WT, eln);

    gemm_final<<<256, 256, 0, stream>>>(M, WT, u, V, out);
}